// Round 2
// baseline (5327.007 us; speedup 1.0000x reference)
//
#include <hip/hip_runtime.h>
#include <hip/hip_bf16.h>
#include <math.h>

using bf16 = __hip_bfloat16;

#define B_   64
#define S_   12
#define N04  307
#define N07  883
#define N08  170
#define BN   (B_ * N04)        // 19648
#define HID  256
#define ENC  256
#define PRE  12
#define GSTRIDE (N04 * 2 * HID) // 157184 flat gates per batch
#define UOFF    (N04 * HID)     // 78592 flat split point

// ---------------- static tensor tables (all shapes compile-time) ----------------
#define NT 38
constexpr int g_sz[NT] = {
    39296, 113024, 21760, 235776, 94249, 779689, 28900,          // vec4,vec7,vec8,feat,adj4,adj7,adj8
    32768, 256, 65536, 256, 256, 256, 1,                          // ex4: W1,b1,W2,b2,g,bt,eps
    32768, 256, 65536, 256, 256, 256, 1,                          // ex7
    32768, 256, 65536, 256, 256, 256, 1,                          // ex8
    131584, 512, 65792, 256, 65536, 1, 131072, 256, 3072, 12      // gruW1,gru_b1,gruW2,gru_b2,featW,featb,linW,linb,outW,outb
};
struct Tables { int off[NT + 1]; int blk[NT + 1]; };
constexpr Tables mk_tables() {
    Tables t{};
    t.off[0] = 0; t.blk[0] = 0;
    for (int i = 0; i < NT; ++i) {
        t.off[i + 1] = t.off[i] + g_sz[i];
        t.blk[i + 1] = t.blk[i] + (g_sz[i] + 1023) / 1024;
    }
    return t;
}
constexpr Tables g_tbl = mk_tables();

// ---------------- dtype sniffer: is the data bf16 or fp32? ----------------
// bf16 data read as bf16: ~99% of N(0,1) values land in (1e-3, 100).
// fp32 data read as bf16: even indices are mantissa bits -> ~50% sane.
__global__ void sniff_kernel(const unsigned short* raw, int* flag)
{
    __shared__ int sh[256];
    int t = threadIdx.x, cnt = 0;
    for (int i = t; i < 2048; i += 256) {
        unsigned int w = ((unsigned int)raw[i]) << 16;
        float a = fabsf(__uint_as_float(w));
        if (a > 1e-3f && a < 100.f) cnt++;
    }
    sh[t] = cnt; __syncthreads();
    for (int off = 128; off > 0; off >>= 1) {
        if (t < off) sh[t] += sh[t + off];
        __syncthreads();
    }
    if (t == 0) *flag = (sh[0] > 1536) ? 1 : 0;  // >75% sane => bf16
}

struct Ptrs { const void* p[NT]; };

__global__ __launch_bounds__(256) void convert_all(Ptrs a, float* arena, const int* flag)
{
    const int bf = *flag;
    int b = blockIdx.x;
    int t = 0;
    while (b >= g_tbl.blk[t + 1]) ++t;            // uniform per block
    const int base = (b - g_tbl.blk[t]) * 1024;
    const int n = g_sz[t];
    const void* src = a.p[t];
    float* dst = arena + g_tbl.off[t];
#pragma unroll
    for (int k = 0; k < 4; ++k) {
        int j = base + k * 256 + threadIdx.x;
        if (j < n)
            dst[j] = bf ? __bfloat162float(((const bf16*)src)[j]) : ((const float*)src)[j];
    }
}

// ---------------- A-load functors (fp32) ----------------
struct ALf32 {
    const float* A; int lda;
    __device__ float operator()(int m, int k) const { return A[(size_t)m * lda + k]; }
};
struct ALnorm {
    const float* h1; const float* mu; const float* rstd; const float* g; const float* bt;
    __device__ float operator()(int m, int k) const {
        return (h1[(size_t)m * HID + k] - mu[k]) * rstd[k] * g[k] + bt[k];
    }
};
struct ALrh {
    const float* gates; const float* h;
    __device__ float operator()(int m, int k) const {
        int b = m / N04, nn = m - b * N04;
        float r = gates[(size_t)b * GSTRIDE + nn * HID + k];
        return r * h[(size_t)m * HID + k];
    }
};
struct ALuhc {
    const float* gates; const float* h; const float* c;
    __device__ float operator()(int m, int k) const {
        int b = m / N04, nn = m - b * N04;
        float u = gates[(size_t)b * GSTRIDE + UOFF + nn * HID + k];
        size_t idx = (size_t)m * HID + k;
        return u * h[idx] + (1.f - u) * c[idx];
    }
};

// ---------------- B-load ----------------
struct BLf32 {
    const float* Bm; int ldb;
    __device__ float operator()(int k, int n) const { return Bm[(size_t)k * ldb + n]; }
};

// ---------------- epilogues ----------------
struct EPstoref {
    float* C; int ldc;
    __device__ void operator()(int m, int n, float v) const { C[(size_t)m * ldc + n] = v; }
};
struct EPbiasf {
    float* C; int ldc; const float* bias;
    __device__ void operator()(int m, int n, float v) const { C[(size_t)m * ldc + n] = v + bias[n]; }
};
struct EPpool {
    float* h1; const float* deg; const float* h0; const float* eps;
    __device__ void operator()(int m, int n, float v) const {
        h1[(size_t)m * HID + n] = v / deg[m] + eps[0] * h0[(size_t)m * HID + n];
    }
};
// extractor final: +b2, write to d_out (dtype per flag) + optional fp32 copy
struct EPextout {
    void* outbase; size_t ooff; float* outf; const float* b2; const int* flag;
    __device__ void operator()(int m, int n, float v) const {
        v += b2[n];
        size_t i = ooff + (size_t)m * ENC + n;
        if (*flag) ((bf16*)outbase)[i] = __float2bfloat16(v);
        else       ((float*)outbase)[i] = v;
        if (outf) outf[(size_t)m * ENC + n] = v;
    }
};
struct EPscalarb {
    float* C; const float* sb;
    __device__ void operator()(int m, int n, float v) const { C[(size_t)m * 256 + n] = v + sb[0]; }
};
struct EPgates {
    float* gates; const float* b1; const float* w1r0; const float* feat; int s;
    __device__ void operator()(int m, int n, float v) const {
        int b = m / N04, nn = m - b * N04;
        float x = feat[((size_t)b * S_ + s) * N04 + nn];
        v += b1[n] + x * w1r0[n];
        gates[(size_t)m * (2 * HID) + n] = 1.f / (1.f + expf(-v));
    }
};
struct EPcand {
    float* c; const float* b2; const float* w2r0; const float* feat; int s;
    __device__ void operator()(int m, int n, float v) const {
        int b = m / N04, nn = m - b * N04;
        float x = feat[((size_t)b * S_ + s) * N04 + nn];
        c[(size_t)m * HID + n] = tanhf(v + b2[n] + x * w2r0[n]);
    }
};
struct EPlin {
    float* hn; const float* lb; const float* fp2;
    __device__ void operator()(int m, int n, float v) const {
        int nn = m % N04;
        hn[(size_t)m * HID + n] = v + lb[n] + fp2[(size_t)nn * HID + n];
    }
};

// ---------------- generic tiled GEMM: 64x64 tile, 4x4 per thread, fp32 accum ----------------
template <typename AL, typename BL, typename EP>
__global__ __launch_bounds__(256) void gemm_t(int M, int N, int K, AL al, BL bl, EP ep)
{
    __shared__ float As[16][68];
    __shared__ float Bs[16][68];
    const int m0 = blockIdx.x * 64;
    const int n0 = blockIdx.y * 64;
    const int t  = threadIdx.x;
    const int tx = t & 15, ty = t >> 4;
    const int a_m = t >> 2;
    const int a_k = (t & 3) << 2;
    const int b_n = t & 63;
    const int b_k = (t >> 6) << 2;
    float acc[4][4] = {{0.f}};

    for (int kt = 0; kt < K; kt += 16) {
        const int gm = m0 + a_m;
#pragma unroll
        for (int i = 0; i < 4; ++i) {
            int gk = kt + a_k + i;
            As[a_k + i][a_m] = (gm < M && gk < K) ? al(gm, gk) : 0.f;
        }
        const int gn = n0 + b_n;
#pragma unroll
        for (int i = 0; i < 4; ++i) {
            int gk = kt + b_k + i;
            Bs[b_k + i][b_n] = (gk < K && gn < N) ? bl(gk, gn) : 0.f;
        }
        __syncthreads();
#pragma unroll
        for (int kk = 0; kk < 16; ++kk) {
            float a[4], b[4];
#pragma unroll
            for (int i = 0; i < 4; ++i) a[i] = As[kk][ty * 4 + i];
#pragma unroll
            for (int j = 0; j < 4; ++j) b[j] = Bs[kk][tx * 4 + j];
#pragma unroll
            for (int i = 0; i < 4; ++i)
#pragma unroll
                for (int j = 0; j < 4; ++j) acc[i][j] += a[i] * b[j];
        }
        __syncthreads();
    }
#pragma unroll
    for (int i = 0; i < 4; ++i) {
        int m = m0 + ty * 4 + i;
        if (m >= M) continue;
#pragma unroll
        for (int j = 0; j < 4; ++j) {
            int n = n0 + tx * 4 + j;
            if (n < N) ep(m, n, acc[i][j]);
        }
    }
}

// ---------------- small kernels ----------------
__global__ void deg_kernel(const float* adj, float* deg, int N)
{
    int row = blockIdx.x;
    float s = 0.f;
    for (int j = threadIdx.x; j < N; j += 64) s += adj[(size_t)row * N + j];
#pragma unroll
    for (int off = 32; off > 0; off >>= 1) s += __shfl_down(s, off, 64);
    if (threadIdx.x == 0) deg[row] = s;
}

__global__ __launch_bounds__(256) void stats_kernel(const float* h1, int N, float* mu, float* rstd)
{
    int j = blockIdx.x;
    int t = threadIdx.x;
    float s = 0.f, ss = 0.f;
    for (int i = t; i < N; i += 256) {
        float v = h1[(size_t)i * HID + j];
        s += v; ss += v * v;
    }
    __shared__ float sh[256], sh2[256];
    sh[t] = s; sh2[t] = ss;
    __syncthreads();
    for (int off = 128; off > 0; off >>= 1) {
        if (t < off) { sh[t] += sh[t + off]; sh2[t] += sh2[t + off]; }
        __syncthreads();
    }
    if (t == 0) {
        float m = sh[0] / (float)N;
        float var = sh2[0] / (float)N - m * m;
        mu[j] = m;
        rstd[j] = rsqrtf(var + 1e-5f);
    }
}

__global__ __launch_bounds__(256) void pred_kernel(const float* h, const float* W, const float* bias,
                                                   void* outbase, const int* flag)
{
    int id = blockIdx.x * 256 + threadIdx.x;
    if (id >= BN * PRE) return;
    int m = id / PRE, p = id - (id / PRE) * PRE;
    float s = bias[p];
    const float* hr = h + (size_t)m * HID;
    for (int k = 0; k < HID; ++k) s += hr[k] * W[k * PRE + p];
    if (*flag) ((bf16*)outbase)[id] = __float2bfloat16(s);
    else       ((float*)outbase)[id] = s;
}

// ---------------- extractor pipeline ----------------
static void run_extract(int N, const float* vec, const float* adj,
                        const float* W1, const float* b1, const float* W2, const float* b2,
                        const float* g, const float* bt, const float* eps,
                        void* outbase, size_t ooff, float* of, const int* flag,
                        float* h0, float* h1, float* deg, float* mu, float* rstd,
                        hipStream_t stream)
{
    int mt = (N + 63) / 64;
    gemm_t<<<dim3(mt, 4), 256, 0, stream>>>(N, 256, 128, ALf32{vec, 128}, BLf32{W1, 256}, EPbiasf{h0, 256, b1});
    deg_kernel<<<N, 64, 0, stream>>>(adj, deg, N);
    gemm_t<<<dim3(mt, 4), 256, 0, stream>>>(N, 256, N, ALf32{adj, N}, BLf32{h0, 256}, EPpool{h1, deg, h0, eps});
    stats_kernel<<<256, 256, 0, stream>>>(h1, N, mu, rstd);
    gemm_t<<<dim3(mt, 4), 256, 0, stream>>>(N, 256, 256, ALnorm{h1, mu, rstd, g, bt}, BLf32{W2, 256},
                                            EPextout{outbase, ooff, of, b2, flag});
}

extern "C" void kernel_launch(void* const* d_in, const int* in_sizes, int n_in,
                              void* d_out, int out_size, void* d_ws, size_t ws_size,
                              hipStream_t stream)
{
    char* wp = (char*)d_ws;
    auto carve = [&](size_t bytes) -> void* {
        void* p = (void*)wp;
        wp += (bytes + 255) & ~(size_t)255;
        return p;
    };
    float* arena = (float*)carve((size_t)g_tbl.off[NT] * 4);
    int*   flag  = (int*)carve(256);
    float* h_a   = (float*)carve((size_t)BN * HID * 4);
    float* h_b   = (float*)carve((size_t)BN * HID * 4);
    float* gates = (float*)carve((size_t)BN * 2 * HID * 4);
    float* cbuf  = (float*)carve((size_t)BN * HID * 4);
    float* eh0   = (float*)carve((size_t)N07 * HID * 4);
    float* eh1   = (float*)carve((size_t)N07 * HID * 4);
    float* degb  = (float*)carve((size_t)N07 * 4);
    float* mub   = (float*)carve(256 * 4);
    float* rstdb = (float*)carve(256 * 4);
    float* f4f   = (float*)carve((size_t)N04 * ENC * 4);
    float* fpre  = (float*)carve((size_t)N04 * ENC * 4);
    float* fp2   = (float*)carve((size_t)N04 * HID * 4);

    // --- dtype sniff + canonical fp32 conversion of all float inputs ---
    sniff_kernel<<<1, 256, 0, stream>>>((const unsigned short*)d_in[0], flag);
    Ptrs ptrs;
    for (int i = 0; i < NT; ++i) ptrs.p[i] = d_in[i];
    convert_all<<<g_tbl.blk[NT], 256, 0, stream>>>(ptrs, arena, flag);

    auto A = [&](int i) -> const float* { return arena + g_tbl.off[i]; };

    // output element offsets (element-indexed; byte stride depends on flag)
    const size_t o_pred = 0;
    const size_t o_f4   = (size_t)B_ * N04 * PRE;
    const size_t o_f7   = o_f4 + (size_t)N04 * ENC;
    const size_t o_f8   = o_f7 + (size_t)N07 * ENC;

    hipMemsetAsync(h_a, 0, (size_t)BN * HID * 4, stream);

    // --- extractors ---
    run_extract(N04, A(0), A(4), A(7), A(8), A(9), A(10), A(11), A(12), A(13),
                d_out, o_f4, f4f, flag, eh0, eh1, degb, mub, rstdb, stream);
    run_extract(N07, A(1), A(5), A(14), A(15), A(16), A(17), A(18), A(19), A(20),
                d_out, o_f7, nullptr, flag, eh0, eh1, degb, mub, rstdb, stream);
    run_extract(N08, A(2), A(6), A(21), A(22), A(23), A(24), A(25), A(26), A(27),
                d_out, o_f8, nullptr, flag, eh0, eh1, degb, mub, rstdb, stream);

    // --- fp2 = (f4 @ feat_W + feat_b) @ lin_W[256:512] (timestep/batch invariant) ---
    gemm_t<<<dim3(5, 4), 256, 0, stream>>>(N04, 256, 256, ALf32{f4f, 256}, BLf32{A(32), 256}, EPscalarb{fpre, A(33)});
    gemm_t<<<dim3(5, 4), 256, 0, stream>>>(N04, 256, 256, ALf32{fpre, 256}, BLf32{A(34) + 256 * 256, 256}, EPstoref{fp2, 256});

    // --- GRU scan ---
    const float* feat = A(3);
    float* hc = h_a;
    float* hn = h_b;
    for (int s = 0; s < S_; ++s) {
        gemm_t<<<dim3(BN / 64, 8), 256, 0, stream>>>(BN, 512, 256,
            ALf32{hc, 256}, BLf32{A(28) + 512, 512}, EPgates{gates, A(29), A(28), feat, s});
        gemm_t<<<dim3(BN / 64, 4), 256, 0, stream>>>(BN, 256, 256,
            ALrh{gates, hc}, BLf32{A(30) + 256, 256}, EPcand{cbuf, A(31), A(30), feat, s});
        gemm_t<<<dim3(BN / 64, 4), 256, 0, stream>>>(BN, 256, 256,
            ALuhc{gates, hc, cbuf}, BLf32{A(34), 256}, EPlin{hn, A(35), fp2});
        float* tmp = hc; hc = hn; hn = tmp;
    }

    // --- pred ---
    pred_kernel<<<(BN * PRE + 255) / 256, 256, 0, stream>>>(hc, A(36), A(37), d_out, flag);
}

// Round 3
// 2155.087 us; speedup vs baseline: 2.4718x; 2.4718x over previous
//
#include <hip/hip_runtime.h>
#include <hip/hip_bf16.h>
#include <math.h>

using bf16 = __hip_bfloat16;
using short8  = __attribute__((ext_vector_type(8))) short;
using float4v = __attribute__((ext_vector_type(4))) float;

#define B_   64
#define S_   12
#define N04  307
#define N07  883
#define N08  170
#define BN   (B_ * N04)        // 19648
#define HID  256
#define ENC  256
#define PRE  12
#define UOFF (N04 * HID)       // 78592 flat split point

// ---------------- static tensor tables ----------------
#define NT 38
constexpr int g_sz[NT] = {
    39296, 113024, 21760, 235776, 94249, 779689, 28900,
    32768, 256, 65536, 256, 256, 256, 1,
    32768, 256, 65536, 256, 256, 256, 1,
    32768, 256, 65536, 256, 256, 256, 1,
    131584, 512, 65792, 256, 65536, 1, 131072, 256, 3072, 12
};
struct Tables { int off[NT + 1]; int blk[NT + 1]; };
constexpr Tables mk_tables() {
    Tables t{};
    t.off[0] = 0; t.blk[0] = 0;
    for (int i = 0; i < NT; ++i) {
        t.off[i + 1] = t.off[i] + g_sz[i];
        t.blk[i + 1] = t.blk[i] + (g_sz[i] + 1023) / 1024;
    }
    return t;
}
constexpr Tables g_tbl = mk_tables();

// ---------------- dtype sniffer ----------------
__global__ void sniff_kernel(const unsigned short* raw, int* flag)
{
    __shared__ int sh[256];
    int t = threadIdx.x, cnt = 0;
    for (int i = t; i < 2048; i += 256) {
        unsigned int w = ((unsigned int)raw[i]) << 16;
        float a = fabsf(__uint_as_float(w));
        if (a > 1e-3f && a < 100.f) cnt++;
    }
    sh[t] = cnt; __syncthreads();
    for (int off = 128; off > 0; off >>= 1) {
        if (t < off) sh[t] += sh[t + off];
        __syncthreads();
    }
    if (t == 0) *flag = (sh[0] > 1536) ? 1 : 0;
}

struct Ptrs { const void* p[NT]; };

__global__ __launch_bounds__(256) void convert_all(Ptrs a, float* arena, const int* flag)
{
    const int bf = *flag;
    int b = blockIdx.x;
    int t = 0;
    while (b >= g_tbl.blk[t + 1]) ++t;
    const int base = (b - g_tbl.blk[t]) * 1024;
    const int n = g_sz[t];
    const void* src = a.p[t];
    float* dst = arena + g_tbl.off[t];
#pragma unroll
    for (int k = 0; k < 4; ++k) {
        int j = base + k * 256 + threadIdx.x;
        if (j < n)
            dst[j] = bf ? __bfloat162float(((const bf16*)src)[j]) : ((const float*)src)[j];
    }
}

// ---------------- weight prep: transposed bf16 B matrices for MFMA ----------------
__global__ __launch_bounds__(256) void prep_weights(const float* w1, const float* w2, const float* wl,
                                                    bf16* WgT, bf16* WcT, bf16* WlT)
{
    int id = blockIdx.x * 256 + threadIdx.x;
    if (id < 131072) {                       // WgT[n][k] = gruW1[1+k][n], n<512,k<256
        int n = id >> 8, k = id & 255;
        WgT[id] = __float2bfloat16(w1[(size_t)(1 + k) * 512 + n]);
    } else if (id < 196608) {                // WcT[n][k] = gruW2[1+k][n]
        int r = id - 131072; int n = r >> 8, k = r & 255;
        WcT[r] = __float2bfloat16(w2[(size_t)(1 + k) * 256 + n]);
    } else if (id < 262144) {                // WlT[n][k] = linW[k][n]
        int r = id - 196608; int n = r >> 8, k = r & 255;
        WlT[r] = __float2bfloat16(wl[(size_t)k * 256 + n]);
    }
}

// ---------------- fp32 functor GEMM (extractors / fp2 — unchanged) ----------------
struct ALf32 {
    const float* A; int lda;
    __device__ float operator()(int m, int k) const { return A[(size_t)m * lda + k]; }
};
struct ALnorm {
    const float* h1; const float* mu; const float* rstd; const float* g; const float* bt;
    __device__ float operator()(int m, int k) const {
        return (h1[(size_t)m * HID + k] - mu[k]) * rstd[k] * g[k] + bt[k];
    }
};
struct BLf32 {
    const float* Bm; int ldb;
    __device__ float operator()(int k, int n) const { return Bm[(size_t)k * ldb + n]; }
};
struct EPstoref {
    float* C; int ldc;
    __device__ void operator()(int m, int n, float v) const { C[(size_t)m * ldc + n] = v; }
};
struct EPbiasf {
    float* C; int ldc; const float* bias;
    __device__ void operator()(int m, int n, float v) const { C[(size_t)m * ldc + n] = v + bias[n]; }
};
struct EPpool {
    float* h1; const float* deg; const float* h0; const float* eps;
    __device__ void operator()(int m, int n, float v) const {
        h1[(size_t)m * HID + n] = v / deg[m] + eps[0] * h0[(size_t)m * HID + n];
    }
};
struct EPextout {
    void* outbase; size_t ooff; float* outf; const float* b2; const int* flag;
    __device__ void operator()(int m, int n, float v) const {
        v += b2[n];
        size_t i = ooff + (size_t)m * ENC + n;
        if (*flag) ((bf16*)outbase)[i] = __float2bfloat16(v);
        else       ((float*)outbase)[i] = v;
        if (outf) outf[(size_t)m * ENC + n] = v;
    }
};
struct EPscalarb {
    float* C; const float* sb;
    __device__ void operator()(int m, int n, float v) const { C[(size_t)m * 256 + n] = v + sb[0]; }
};

template <typename AL, typename BL, typename EP>
__global__ __launch_bounds__(256) void gemm_t(int M, int N, int K, AL al, BL bl, EP ep)
{
    __shared__ float As[16][68];
    __shared__ float Bs[16][68];
    const int m0 = blockIdx.x * 64;
    const int n0 = blockIdx.y * 64;
    const int t  = threadIdx.x;
    const int tx = t & 15, ty = t >> 4;
    const int a_m = t >> 2;
    const int a_k = (t & 3) << 2;
    const int b_n = t & 63;
    const int b_k = (t >> 6) << 2;
    float acc[4][4] = {{0.f}};

    for (int kt = 0; kt < K; kt += 16) {
        const int gm = m0 + a_m;
#pragma unroll
        for (int i = 0; i < 4; ++i) {
            int gk = kt + a_k + i;
            As[a_k + i][a_m] = (gm < M && gk < K) ? al(gm, gk) : 0.f;
        }
        const int gn = n0 + b_n;
#pragma unroll
        for (int i = 0; i < 4; ++i) {
            int gk = kt + b_k + i;
            Bs[b_k + i][b_n] = (gk < K && gn < N) ? bl(gk, gn) : 0.f;
        }
        __syncthreads();
#pragma unroll
        for (int kk = 0; kk < 16; ++kk) {
            float a[4], b[4];
#pragma unroll
            for (int i = 0; i < 4; ++i) a[i] = As[kk][ty * 4 + i];
#pragma unroll
            for (int j = 0; j < 4; ++j) b[j] = Bs[kk][tx * 4 + j];
#pragma unroll
            for (int i = 0; i < 4; ++i)
#pragma unroll
                for (int j = 0; j < 4; ++j) acc[i][j] += a[i] * b[j];
        }
        __syncthreads();
    }
#pragma unroll
    for (int i = 0; i < 4; ++i) {
        int m = m0 + ty * 4 + i;
        if (m >= M) continue;
#pragma unroll
        for (int j = 0; j < 4; ++j) {
            int n = n0 + tx * 4 + j;
            if (n < N) ep(m, n, acc[i][j]);
        }
    }
}

// ---------------- MFMA GEMM: 128x128 tile, K=256 fixed, A [M][256] bf16, BT [N][256] bf16 ----------------
// LDS stride 40 shorts (80 B): 16B-aligned b128 frag reads, conflict-free (8-row bank period covers all 32).
struct EPgates2 {   // gates = sigmoid(.); emit rh (bf16, flat-split r) and u (fp32)
    bf16* rh; float* ubuf; const float* hF;
    const float* b1; const float* w1r0; const float* feat; int s;
    __device__ void operator()(int m, int n, float v) const {
        int b = m / N04, nn = m - b * N04;
        float x = feat[((size_t)b * S_ + s) * N04 + nn];
        float g = 1.f / (1.f + expf(-(v + b1[n] + x * w1r0[n])));
        int p = nn * 512 + n;                 // flat per-batch gate index
        int base = b * UOFF;
        if (p < UOFF) {
            int idx = base + p;               // node = p>>8, col = p&255 => contiguous
            rh[idx] = __float2bfloat16(g * hF[idx]);
        } else {
            ubuf[base + (p - UOFF)] = g;
        }
    }
};
struct EPcand2 {    // c = tanh(.); emit uhc = u*h + (1-u)*c (bf16)
    bf16* uhc; const float* ubuf; const float* hF;
    const float* b2; const float* w2r0; const float* feat; int s;
    __device__ void operator()(int m, int n, float v) const {
        int b = m / N04, nn = m - b * N04;
        float x = feat[((size_t)b * S_ + s) * N04 + nn];
        float c = tanhf(v + b2[n] + x * w2r0[n]);
        size_t idx = (size_t)m * 256 + n;
        float u = ubuf[idx];
        uhc[idx] = __float2bfloat16(u * hF[idx] + (1.f - u) * c);
    }
};
struct EPlin2 {     // h_next = v + lin_b + fp2 ; write fp32 + bf16 copies
    float* hF; bf16* hB; const float* lb; const float* fp2;
    __device__ void operator()(int m, int n, float v) const {
        int nn = m % N04;
        v += lb[n] + fp2[(size_t)nn * 256 + n];
        size_t idx = (size_t)m * 256 + n;
        hF[idx] = v;
        hB[idx] = __float2bfloat16(v);
    }
};

template <typename EP>
__global__ __launch_bounds__(256) void gemm_mfma(int M, const unsigned short* __restrict__ Abf,
                                                 const unsigned short* __restrict__ BT, EP ep)
{
    __shared__ __align__(16) unsigned short As[128 * 40];
    __shared__ __align__(16) unsigned short Bs[128 * 40];
    const int m0 = blockIdx.x * 128;
    const int n0 = blockIdx.y * 128;
    const int t = threadIdx.x;
    const int srow  = t >> 1;            // 0..127
    const int skoff = (t & 1) * 16;      // 0 or 16 (shorts)
    const int lane = t & 63;
    const int w  = t >> 6;               // wave 0..3
    const int wm = (w & 1) * 64;
    const int wn = (w >> 1) * 64;
    const int l15 = lane & 15;
    const int l4  = lane >> 4;

    float4v acc[4][4];
#pragma unroll
    for (int i = 0; i < 4; ++i)
#pragma unroll
        for (int j = 0; j < 4; ++j) acc[i][j] = (float4v)(0.f);

    const int gm = m0 + srow;
    const bool avalid = (gm < M);
    const unsigned short* aptr = Abf + (size_t)gm * 256 + skoff;
    const unsigned short* bptr = BT + (size_t)(n0 + srow) * 256 + skoff;
    unsigned short* asw = &As[srow * 40 + skoff];
    unsigned short* bsw = &Bs[srow * 40 + skoff];

    for (int kt = 0; kt < 256; kt += 32) {
        uint4 av0 = avalid ? *(const uint4*)(aptr + kt)     : make_uint4(0, 0, 0, 0);
        uint4 av1 = avalid ? *(const uint4*)(aptr + kt + 8) : make_uint4(0, 0, 0, 0);
        uint4 bv0 = *(const uint4*)(bptr + kt);
        uint4 bv1 = *(const uint4*)(bptr + kt + 8);
        __syncthreads();                 // previous iter's frag reads done
        *(uint4*)(asw)     = av0;
        *(uint4*)(asw + 8) = av1;
        *(uint4*)(bsw)     = bv0;
        *(uint4*)(bsw + 8) = bv1;
        __syncthreads();
        short8 af[4], bq[4];
#pragma unroll
        for (int mi = 0; mi < 4; ++mi)
            af[mi] = *(const short8*)&As[(wm + mi * 16 + l15) * 40 + l4 * 8];
#pragma unroll
        for (int ni = 0; ni < 4; ++ni)
            bq[ni] = *(const short8*)&Bs[(wn + ni * 16 + l15) * 40 + l4 * 8];
#pragma unroll
        for (int mi = 0; mi < 4; ++mi)
#pragma unroll
            for (int ni = 0; ni < 4; ++ni)
                acc[mi][ni] = __builtin_amdgcn_mfma_f32_16x16x32_bf16(af[mi], bq[ni], acc[mi][ni], 0, 0, 0);
    }
#pragma unroll
    for (int mi = 0; mi < 4; ++mi) {
#pragma unroll
        for (int r = 0; r < 4; ++r) {
            int m = m0 + wm + mi * 16 + l4 * 4 + r;
            if (m >= M) continue;
#pragma unroll
            for (int ni = 0; ni < 4; ++ni) {
                int n = n0 + wn + ni * 16 + l15;
                ep(m, n, acc[mi][ni][r]);
            }
        }
    }
}

// ---------------- small kernels ----------------
__global__ void deg_kernel(const float* adj, float* deg, int N)
{
    int row = blockIdx.x;
    float s = 0.f;
    for (int j = threadIdx.x; j < N; j += 64) s += adj[(size_t)row * N + j];
#pragma unroll
    for (int off = 32; off > 0; off >>= 1) s += __shfl_down(s, off, 64);
    if (threadIdx.x == 0) deg[row] = s;
}

__global__ __launch_bounds__(256) void stats_kernel(const float* h1, int N, float* mu, float* rstd)
{
    int j = blockIdx.x;
    int t = threadIdx.x;
    float s = 0.f, ss = 0.f;
    for (int i = t; i < N; i += 256) {
        float v = h1[(size_t)i * HID + j];
        s += v; ss += v * v;
    }
    __shared__ float sh[256], sh2[256];
    sh[t] = s; sh2[t] = ss;
    __syncthreads();
    for (int off = 128; off > 0; off >>= 1) {
        if (t < off) { sh[t] += sh[t + off]; sh2[t] += sh2[t + off]; }
        __syncthreads();
    }
    if (t == 0) {
        float m = sh[0] / (float)N;
        float var = sh2[0] / (float)N - m * m;
        mu[j] = m;
        rstd[j] = rsqrtf(var + 1e-5f);
    }
}

__global__ __launch_bounds__(256) void pred_kernel(const float* h, const float* W, const float* bias,
                                                   void* outbase, const int* flag)
{
    int id = blockIdx.x * 256 + threadIdx.x;
    if (id >= BN * PRE) return;
    int m = id / PRE, p = id - (id / PRE) * PRE;
    float s = bias[p];
    const float* hr = h + (size_t)m * HID;
    for (int k = 0; k < HID; ++k) s += hr[k] * W[k * PRE + p];
    if (*flag) ((bf16*)outbase)[id] = __float2bfloat16(s);
    else       ((float*)outbase)[id] = s;
}

// ---------------- extractor pipeline ----------------
static void run_extract(int N, const float* vec, const float* adj,
                        const float* W1, const float* b1, const float* W2, const float* b2,
                        const float* g, const float* bt, const float* eps,
                        void* outbase, size_t ooff, float* of, const int* flag,
                        float* h0, float* h1, float* deg, float* mu, float* rstd,
                        hipStream_t stream)
{
    int mt = (N + 63) / 64;
    gemm_t<<<dim3(mt, 4), 256, 0, stream>>>(N, 256, 128, ALf32{vec, 128}, BLf32{W1, 256}, EPbiasf{h0, 256, b1});
    deg_kernel<<<N, 64, 0, stream>>>(adj, deg, N);
    gemm_t<<<dim3(mt, 4), 256, 0, stream>>>(N, 256, N, ALf32{adj, N}, BLf32{h0, 256}, EPpool{h1, deg, h0, eps});
    stats_kernel<<<256, 256, 0, stream>>>(h1, N, mu, rstd);
    gemm_t<<<dim3(mt, 4), 256, 0, stream>>>(N, 256, 256, ALnorm{h1, mu, rstd, g, bt}, BLf32{W2, 256},
                                            EPextout{outbase, ooff, of, b2, flag});
}

extern "C" void kernel_launch(void* const* d_in, const int* in_sizes, int n_in,
                              void* d_out, int out_size, void* d_ws, size_t ws_size,
                              hipStream_t stream)
{
    char* wp = (char*)d_ws;
    auto carve = [&](size_t bytes) -> void* {
        void* p = (void*)wp;
        wp += (bytes + 255) & ~(size_t)255;
        return p;
    };
    float* arena = (float*)carve((size_t)g_tbl.off[NT] * 4);
    int*   flag  = (int*)carve(256);
    float* h_a   = (float*)carve((size_t)BN * HID * 4);
    float* h_b   = (float*)carve((size_t)BN * HID * 4);
    bf16*  hb_a  = (bf16*)carve((size_t)BN * HID * 2);
    bf16*  hb_b  = (bf16*)carve((size_t)BN * HID * 2);
    bf16*  rh    = (bf16*)carve((size_t)BN * HID * 2);
    bf16*  uhc   = (bf16*)carve((size_t)BN * HID * 2);
    float* ubuf  = (float*)carve((size_t)BN * HID * 4);
    bf16*  WgT   = (bf16*)carve((size_t)512 * 256 * 2);
    bf16*  WcT   = (bf16*)carve((size_t)256 * 256 * 2);
    bf16*  WlT   = (bf16*)carve((size_t)256 * 256 * 2);
    float* eh0   = (float*)carve((size_t)N07 * HID * 4);
    float* eh1   = (float*)carve((size_t)N07 * HID * 4);
    float* degb  = (float*)carve((size_t)N07 * 4);
    float* mub   = (float*)carve(256 * 4);
    float* rstdb = (float*)carve(256 * 4);
    float* f4f   = (float*)carve((size_t)N04 * ENC * 4);
    float* fpre  = (float*)carve((size_t)N04 * ENC * 4);
    float* fp2   = (float*)carve((size_t)N04 * HID * 4);

    // --- dtype sniff + canonical fp32 conversion ---
    sniff_kernel<<<1, 256, 0, stream>>>((const unsigned short*)d_in[0], flag);
    Ptrs ptrs;
    for (int i = 0; i < NT; ++i) ptrs.p[i] = d_in[i];
    convert_all<<<g_tbl.blk[NT], 256, 0, stream>>>(ptrs, arena, flag);

    auto A = [&](int i) -> const float* { return arena + g_tbl.off[i]; };

    // transposed bf16 weights for the MFMA GEMMs
    prep_weights<<<1024, 256, 0, stream>>>(A(28), A(30), A(34), WgT, WcT, WlT);

    const size_t o_f4 = (size_t)B_ * N04 * PRE;
    const size_t o_f7 = o_f4 + (size_t)N04 * ENC;
    const size_t o_f8 = o_f7 + (size_t)N07 * ENC;

    hipMemsetAsync(h_a, 0, (size_t)BN * HID * 4, stream);
    hipMemsetAsync(hb_a, 0, (size_t)BN * HID * 2, stream);

    // --- extractors (fp32 path, unchanged) ---
    run_extract(N04, A(0), A(4), A(7), A(8), A(9), A(10), A(11), A(12), A(13),
                d_out, o_f4, f4f, flag, eh0, eh1, degb, mub, rstdb, stream);
    run_extract(N07, A(1), A(5), A(14), A(15), A(16), A(17), A(18), A(19), A(20),
                d_out, o_f7, nullptr, flag, eh0, eh1, degb, mub, rstdb, stream);
    run_extract(N08, A(2), A(6), A(21), A(22), A(23), A(24), A(25), A(26), A(27),
                d_out, o_f8, nullptr, flag, eh0, eh1, degb, mub, rstdb, stream);

    // --- fp2 = (f4 @ feat_W + feat_b) @ lin_W[256:512] ---
    gemm_t<<<dim3(5, 4), 256, 0, stream>>>(N04, 256, 256, ALf32{f4f, 256}, BLf32{A(32), 256}, EPscalarb{fpre, A(33)});
    gemm_t<<<dim3(5, 4), 256, 0, stream>>>(N04, 256, 256, ALf32{fpre, 256}, BLf32{A(34) + 256 * 256, 256}, EPstoref{fp2, 256});

    // --- GRU scan: 3 MFMA GEMMs per step, all elementwise fused in epilogues ---
    const float* feat = A(3);
    float* hcF = h_a;  bf16* hcB = hb_a;
    float* hnF = h_b;  bf16* hnB = hb_b;
    const int MB = (BN + 127) / 128;   // 154
    for (int s = 0; s < S_; ++s) {
        gemm_mfma<<<dim3(MB, 4), 256, 0, stream>>>(BN, (const unsigned short*)hcB, (const unsigned short*)WgT,
            EPgates2{rh, ubuf, hcF, A(29), A(28), feat, s});
        gemm_mfma<<<dim3(MB, 2), 256, 0, stream>>>(BN, (const unsigned short*)rh, (const unsigned short*)WcT,
            EPcand2{uhc, ubuf, hcF, A(31), A(30), feat, s});
        gemm_mfma<<<dim3(MB, 2), 256, 0, stream>>>(BN, (const unsigned short*)uhc, (const unsigned short*)WlT,
            EPlin2{hnF, hnB, A(35), fp2});
        float* tf = hcF; hcF = hnF; hnF = tf;
        bf16*  tb = hcB; hcB = hnB; hnB = tb;
    }

    // --- pred ---
    pred_kernel<<<(BN * PRE + 255) / 256, 256, 0, stream>>>(hcF, A(36), A(37), d_out, flag);
}

// Round 5
// 1623.533 us; speedup vs baseline: 3.2811x; 1.3274x over previous
//
#include <hip/hip_runtime.h>
#include <hip/hip_bf16.h>
#include <math.h>

using bf16 = __hip_bfloat16;
using short8  = __attribute__((ext_vector_type(8))) short;
using float4v = __attribute__((ext_vector_type(4))) float;

#define B_   64
#define S_   12
#define N04  307
#define N07  883
#define N08  170
#define BN   (B_ * N04)        // 19648
#define HID  256
#define ENC  256
#define PRE  12
#define UOFF (N04 * HID)       // 78592 flat split point

// extractor geometry (K padded to x64 for MFMA)
// NOTE: plain constexpr (NOT __constant__) — host shadow of __constant__ is
// zero-initialized in HIP-clang, and kernel_launch reads these on the host.
constexpr int c_Mi[3]   = {N04, N07, N08};
constexpr int c_Kp[3]   = {320, 896, 192};
constexpr int c_Moff[3] = {0, N04, N04 + N07};
constexpr int c_Aoff[3] = {0, N04 * 320, N04 * 320 + N07 * 896};
constexpr int c_Cb[3]   = {0, 320, 320 + 896};
#define MTOT  (N04 + N07 + N08)   // 1360
#define H0T_LD 1408

// ---------------- static tensor tables ----------------
#define NT 38
constexpr int g_sz[NT] = {
    39296, 113024, 21760, 235776, 94249, 779689, 28900,
    32768, 256, 65536, 256, 256, 256, 1,
    32768, 256, 65536, 256, 256, 256, 1,
    32768, 256, 65536, 256, 256, 256, 1,
    131584, 512, 65792, 256, 65536, 1, 131072, 256, 3072, 12
};
struct Tables { int off[NT + 1]; int blk[NT + 1]; };
constexpr Tables mk_tables() {
    Tables t{};
    t.off[0] = 0; t.blk[0] = 0;
    for (int i = 0; i < NT; ++i) {
        t.off[i + 1] = t.off[i] + g_sz[i];
        t.blk[i + 1] = t.blk[i] + (g_sz[i] + 1023) / 1024;
    }
    return t;
}
constexpr Tables g_tbl = mk_tables();

// ---------------- dtype sniffer ----------------
__global__ void sniff_kernel(const unsigned short* raw, int* flag)
{
    __shared__ int sh[256];
    int t = threadIdx.x, cnt = 0;
    for (int i = t; i < 2048; i += 256) {
        unsigned int w = ((unsigned int)raw[i]) << 16;
        float a = fabsf(__uint_as_float(w));
        if (a > 1e-3f && a < 100.f) cnt++;
    }
    sh[t] = cnt; __syncthreads();
    for (int off = 128; off > 0; off >>= 1) {
        if (t < off) sh[t] += sh[t + off];
        __syncthreads();
    }
    if (t == 0) *flag = (sh[0] > 1536) ? 1 : 0;
}

struct Ptrs { const void* p[NT]; };

__global__ __launch_bounds__(256) void convert_all(Ptrs a, float* arena, const int* flag)
{
    const int bf = *flag;
    int b = blockIdx.x;
    int t = 0;
    while (b >= g_tbl.blk[t + 1]) ++t;
    const int base = (b - g_tbl.blk[t]) * 1024;
    const int n = g_sz[t];
    const void* src = a.p[t];
    float* dst = arena + g_tbl.off[t];
#pragma unroll
    for (int k = 0; k < 4; ++k) {
        int j = base + k * 256 + threadIdx.x;
        if (j < n)
            dst[j] = bf ? __bfloat162float(((const bf16*)src)[j]) : ((const float*)src)[j];
    }
}

// ---------------- weight prep: GRU transposed bf16 B matrices ----------------
__global__ __launch_bounds__(256) void prep_weights(const float* w1, const float* w2, const float* wl,
                                                    bf16* WgT, bf16* WcT, bf16* WlT)
{
    int id = blockIdx.x * 256 + threadIdx.x;
    if (id < 131072) {
        int n = id >> 8, k = id & 255;
        WgT[id] = __float2bfloat16(w1[(size_t)(1 + k) * 512 + n]);
    } else if (id < 196608) {
        int r = id - 131072; int n = r >> 8, k = r & 255;
        WcT[r] = __float2bfloat16(w2[(size_t)(1 + k) * 256 + n]);
    } else if (id < 262144) {
        int r = id - 196608; int n = r >> 8, k = r & 255;
        WlT[r] = __float2bfloat16(wl[(size_t)k * 256 + n]);
    }
}

// ---------------- extractor operand prep ----------------
__global__ __launch_bounds__(256) void prep_adjB(const float* a4, const float* a7, const float* a8, bf16* adjB)
{
    int z = blockIdx.z;
    int Mi = c_Mi[z], Kp = c_Kp[z];
    int m = blockIdx.x;
    if (m >= Mi) return;
    const float* src = (z == 0) ? a4 : (z == 1) ? a7 : a8;
    bf16* dst = adjB + c_Aoff[z] + (size_t)m * Kp;
    for (int c = threadIdx.x; c < Kp; c += 256)
        dst[c] = (c < Mi) ? __float2bfloat16(src[(size_t)m * Mi + c]) : __float2bfloat16(0.f);
}

__global__ __launch_bounds__(256) void prep_transposes(
    const float* v4, const float* v7, const float* v8,
    const float* w1a, const float* w1b, const float* w1c,
    const float* w2a, const float* w2b, const float* w2c,
    const float* featW, const float* linW, const float* outW,
    bf16* vecB, bf16* W1T, bf16* W2T, bf16* featWT, bf16* linW2T, bf16* outWT)
{
    int id = blockIdx.x * 256 + threadIdx.x;
    if (id < 174080) {                       // vecB [1360][128]
        int r = id >> 7, c = id & 127;
        float v = (r < N04) ? v4[(size_t)r * 128 + c]
                : (r < N04 + N07) ? v7[(size_t)(r - N04) * 128 + c]
                : v8[(size_t)(r - N04 - N07) * 128 + c];
        vecB[id] = __float2bfloat16(v);
    } else if (id < 174080 + 98304) {        // W1T [3][256][128]
        int r = id - 174080; int z = r >> 15; int rem = r & 32767;
        int n = rem >> 7, k = rem & 127;
        const float* w = (z == 0) ? w1a : (z == 1) ? w1b : w1c;
        W1T[r] = __float2bfloat16(w[(size_t)k * 256 + n]);
    } else if (id < 272384 + 196608) {       // W2T [3][256][256]
        int r = id - 272384; int z = r >> 16; int rem = r & 65535;
        int n = rem >> 8, k = rem & 255;
        const float* w = (z == 0) ? w2a : (z == 1) ? w2b : w2c;
        W2T[r] = __float2bfloat16(w[(size_t)k * 256 + n]);
    } else if (id < 468992 + 65536) {        // featWT
        int r = id - 468992; int n = r >> 8, k = r & 255;
        featWT[r] = __float2bfloat16(featW[(size_t)k * 256 + n]);
    } else if (id < 534528 + 65536) {        // linW2T = linW[256:512]^T
        int r = id - 534528; int n = r >> 8, k = r & 255;
        linW2T[r] = __float2bfloat16(linW[(size_t)(256 + k) * 256 + n]);
    } else if (id < 600064 + 16384) {        // outWT [64][256], rows 12..63 zero
        int r = id - 600064; int p = r >> 8, k = r & 255;
        outWT[r] = __float2bfloat16((p < PRE) ? outW[(size_t)k * PRE + p] : 0.f);
    }
}
#define PREP_T_TOT (600064 + 16384)

// ---------------- 64x64-tile MFMA GEMM, z-merged, runtime K ----------------
struct GemmZ {
    const unsigned short* A[3];
    const unsigned short* BT[3];
    int M[3]; int K[3]; int lda[3]; int ldb[3];
};

template <typename EP>
__global__ __launch_bounds__(256) void gemm_mfma64(GemmZ p, int Nv, EP ep)
{
    const int z = blockIdx.z;
    const int M = p.M[z], K = p.K[z], lda = p.lda[z], ldb = p.ldb[z];
    const int m0 = blockIdx.x * 64;
    const int n0 = blockIdx.y * 64;
    if (m0 >= M) return;
    __shared__ __align__(16) unsigned short As[64 * 72];
    __shared__ __align__(16) unsigned short Bs[64 * 72];
    const int t = threadIdx.x;
    const int srow  = t >> 2;           // 0..63
    const int skoff = (t & 3) * 16;     // 0,16,32,48 shorts
    const int lane = t & 63;
    const int w  = t >> 6;
    const int wm = (w & 1) * 32;
    const int wn = (w >> 1) * 32;
    const int l15 = lane & 15;
    const int l4  = lane >> 4;

    float4v acc[2][2];
#pragma unroll
    for (int i = 0; i < 2; ++i)
#pragma unroll
        for (int j = 0; j < 2; ++j) acc[i][j] = (float4v)(0.f);

    const int gm = m0 + srow;
    const bool avalid = (gm < M);
    const unsigned short* aptr = p.A[z]  + (size_t)gm * lda + skoff;
    const unsigned short* bptr = p.BT[z] + (size_t)(n0 + srow) * ldb + skoff;
    unsigned short* asw = &As[srow * 72 + skoff];
    unsigned short* bsw = &Bs[srow * 72 + skoff];
    const uint4 z4 = {0, 0, 0, 0};

    for (int kt = 0; kt < K; kt += 64) {
        uint4 av0 = avalid ? *(const uint4*)(aptr + kt)     : z4;
        uint4 av1 = avalid ? *(const uint4*)(aptr + kt + 8) : z4;
        uint4 bv0 = *(const uint4*)(bptr + kt);
        uint4 bv1 = *(const uint4*)(bptr + kt + 8);
        __syncthreads();
        *(uint4*)(asw)     = av0;
        *(uint4*)(asw + 8) = av1;
        *(uint4*)(bsw)     = bv0;
        *(uint4*)(bsw + 8) = bv1;
        __syncthreads();
#pragma unroll
        for (int ks = 0; ks < 2; ++ks) {
            short8 af[2], bq[2];
#pragma unroll
            for (int mi = 0; mi < 2; ++mi)
                af[mi] = *(const short8*)&As[(wm + mi * 16 + l15) * 72 + ks * 32 + l4 * 8];
#pragma unroll
            for (int ni = 0; ni < 2; ++ni)
                bq[ni] = *(const short8*)&Bs[(wn + ni * 16 + l15) * 72 + ks * 32 + l4 * 8];
#pragma unroll
            for (int mi = 0; mi < 2; ++mi)
#pragma unroll
                for (int ni = 0; ni < 2; ++ni)
                    acc[mi][ni] = __builtin_amdgcn_mfma_f32_16x16x32_bf16(af[mi], bq[ni], acc[mi][ni], 0, 0, 0);
        }
    }
#pragma unroll
    for (int mi = 0; mi < 2; ++mi) {
#pragma unroll
        for (int r = 0; r < 4; ++r) {
            int m = m0 + wm + mi * 16 + l4 * 4 + r;
            if (m >= M) continue;
#pragma unroll
            for (int ni = 0; ni < 2; ++ni) {
                int n = n0 + wn + ni * 16 + l15;
                if (n < Nv) ep(z, m, n, acc[mi][ni][r]);
            }
        }
    }
}

// extractor epilogues
struct EPg1 {   // h0 = vec@W1 + b1 ; write fp32 + transposed bf16
    const float* b1[3]; float* h0F; bf16* h0T;
    __device__ void operator()(int z, int m, int n, float v) const {
        v += b1[z][n];
        int gr = c_Moff[z] + m;
        h0F[(size_t)gr * 256 + n] = v;
        h0T[(size_t)n * H0T_LD + c_Cb[z] + m] = __float2bfloat16(v);
    }
};
struct EPg2 {   // h1 = pooled/deg + eps*h0
    const float* deg; const float* h0F; float* h1F; const float* eps[3];
    __device__ void operator()(int z, int m, int n, float v) const {
        int gr = c_Moff[z] + m;
        h1F[(size_t)gr * 256 + n] = v / deg[gr] + eps[z][0] * h0F[(size_t)gr * 256 + n];
    }
};
struct EPg3 {   // f = norm(h1)@W2 + b2 -> d_out (+ f4 bf16 copy for fp2)
    const float* b2[3]; void* outbase; size_t ooff[3]; const int* flag; bf16* f4B;
    __device__ void operator()(int z, int m, int n, float v) const {
        v += b2[z][n];
        size_t i = ooff[z] + (size_t)m * 256 + n;
        if (*flag) ((bf16*)outbase)[i] = __float2bfloat16(v);
        else       ((float*)outbase)[i] = v;
        if (z == 0) f4B[(size_t)m * 256 + n] = __float2bfloat16(v);
    }
};
struct EPfp2a { // fpre = f4@featW + featb (bf16)
    const float* sb; bf16* fpreB;
    __device__ void operator()(int z, int m, int n, float v) const {
        fpreB[(size_t)m * 256 + n] = __float2bfloat16(v + sb[0]);
    }
};
struct EPfp2b { // fp2 = fpre@linW[256:] (fp32)
    float* fp2;
    __device__ void operator()(int z, int m, int n, float v) const {
        fp2[(size_t)m * 256 + n] = v;
    }
};
struct EPpred { // pred = h@outW + outb -> d_out
    const float* ob; void* outbase; const int* flag;
    __device__ void operator()(int z, int m, int n, float v) const {
        v += ob[n];
        size_t i = (size_t)m * PRE + n;
        if (*flag) ((bf16*)outbase)[i] = __float2bfloat16(v);
        else       ((float*)outbase)[i] = v;
    }
};

// ---------------- 128x128 MFMA GEMM (GRU, K=256 fixed) ----------------
struct EPgates2 {
    bf16* rh; float* ubuf; const float* hF;
    const float* b1; const float* w1r0; const float* feat; int s;
    __device__ void operator()(int m, int n, float v) const {
        int b = m / N04, nn = m - b * N04;
        float x = feat[((size_t)b * S_ + s) * N04 + nn];
        float g = 1.f / (1.f + expf(-(v + b1[n] + x * w1r0[n])));
        int p = nn * 512 + n;
        int base = b * UOFF;
        if (p < UOFF) {
            int idx = base + p;
            rh[idx] = __float2bfloat16(g * hF[idx]);
        } else {
            ubuf[base + (p - UOFF)] = g;
        }
    }
};
struct EPcand2 {
    bf16* uhc; const float* ubuf; const float* hF;
    const float* b2; const float* w2r0; const float* feat; int s;
    __device__ void operator()(int m, int n, float v) const {
        int b = m / N04, nn = m - b * N04;
        float x = feat[((size_t)b * S_ + s) * N04 + nn];
        float c = tanhf(v + b2[n] + x * w2r0[n]);
        size_t idx = (size_t)m * 256 + n;
        float u = ubuf[idx];
        uhc[idx] = __float2bfloat16(u * hF[idx] + (1.f - u) * c);
    }
};
struct EPlin2 {
    float* hF; bf16* hB; const float* lb; const float* fp2;
    __device__ void operator()(int m, int n, float v) const {
        int nn = m % N04;
        v += lb[n] + fp2[(size_t)nn * 256 + n];
        size_t idx = (size_t)m * 256 + n;
        hF[idx] = v;
        hB[idx] = __float2bfloat16(v);
    }
};

template <typename EP>
__global__ __launch_bounds__(256) void gemm_mfma(int M, const unsigned short* __restrict__ Abf,
                                                 const unsigned short* __restrict__ BT, EP ep)
{
    __shared__ __align__(16) unsigned short As[128 * 40];
    __shared__ __align__(16) unsigned short Bs[128 * 40];
    const int m0 = blockIdx.x * 128;
    const int n0 = blockIdx.y * 128;
    const int t = threadIdx.x;
    const int srow  = t >> 1;
    const int skoff = (t & 1) * 16;
    const int lane = t & 63;
    const int w  = t >> 6;
    const int wm = (w & 1) * 64;
    const int wn = (w >> 1) * 64;
    const int l15 = lane & 15;
    const int l4  = lane >> 4;

    float4v acc[4][4];
#pragma unroll
    for (int i = 0; i < 4; ++i)
#pragma unroll
        for (int j = 0; j < 4; ++j) acc[i][j] = (float4v)(0.f);

    const int gm = m0 + srow;
    const bool avalid = (gm < M);
    const unsigned short* aptr = Abf + (size_t)gm * 256 + skoff;
    const unsigned short* bptr = BT + (size_t)(n0 + srow) * 256 + skoff;
    unsigned short* asw = &As[srow * 40 + skoff];
    unsigned short* bsw = &Bs[srow * 40 + skoff];
    const uint4 z4 = {0, 0, 0, 0};

    for (int kt = 0; kt < 256; kt += 32) {
        uint4 av0 = avalid ? *(const uint4*)(aptr + kt)     : z4;
        uint4 av1 = avalid ? *(const uint4*)(aptr + kt + 8) : z4;
        uint4 bv0 = *(const uint4*)(bptr + kt);
        uint4 bv1 = *(const uint4*)(bptr + kt + 8);
        __syncthreads();
        *(uint4*)(asw)     = av0;
        *(uint4*)(asw + 8) = av1;
        *(uint4*)(bsw)     = bv0;
        *(uint4*)(bsw + 8) = bv1;
        __syncthreads();
        short8 af[4], bq[4];
#pragma unroll
        for (int mi = 0; mi < 4; ++mi)
            af[mi] = *(const short8*)&As[(wm + mi * 16 + l15) * 40 + l4 * 8];
#pragma unroll
        for (int ni = 0; ni < 4; ++ni)
            bq[ni] = *(const short8*)&Bs[(wn + ni * 16 + l15) * 40 + l4 * 8];
#pragma unroll
        for (int mi = 0; mi < 4; ++mi)
#pragma unroll
            for (int ni = 0; ni < 4; ++ni)
                acc[mi][ni] = __builtin_amdgcn_mfma_f32_16x16x32_bf16(af[mi], bq[ni], acc[mi][ni], 0, 0, 0);
    }
#pragma unroll
    for (int mi = 0; mi < 4; ++mi) {
#pragma unroll
        for (int r = 0; r < 4; ++r) {
            int m = m0 + wm + mi * 16 + l4 * 4 + r;
            if (m >= M) continue;
#pragma unroll
            for (int ni = 0; ni < 4; ++ni) {
                int n = n0 + wn + ni * 16 + l15;
                ep(m, n, acc[mi][ni][r]);
            }
        }
    }
}

// ---------------- merged small kernels ----------------
__global__ void deg_all(const float* a4, const float* a7, const float* a8, float* deg)
{
    int z = blockIdx.z;
    int Mi = c_Mi[z];
    int row = blockIdx.x;
    if (row >= Mi) return;
    const float* adj = (z == 0) ? a4 : (z == 1) ? a7 : a8;
    float s = 0.f;
    for (int j = threadIdx.x; j < Mi; j += 64) s += adj[(size_t)row * Mi + j];
#pragma unroll
    for (int off = 32; off > 0; off >>= 1) s += __shfl_down(s, off, 64);
    if (threadIdx.x == 0) deg[c_Moff[z] + row] = s;
}

__global__ __launch_bounds__(256) void stats_all(const float* h1F, float* mu, float* rstd)
{
    int z = blockIdx.z;
    int Mi = c_Mi[z], moff = c_Moff[z];
    int j = blockIdx.x;
    int t = threadIdx.x;
    float s = 0.f, ss = 0.f;
    for (int i = t; i < Mi; i += 256) {
        float v = h1F[(size_t)(moff + i) * 256 + j];
        s += v; ss += v * v;
    }
    __shared__ float sh[256], sh2[256];
    sh[t] = s; sh2[t] = ss;
    __syncthreads();
    for (int off = 128; off > 0; off >>= 1) {
        if (t < off) { sh[t] += sh[t + off]; sh2[t] += sh2[t + off]; }
        __syncthreads();
    }
    if (t == 0) {
        float m = sh[0] / (float)Mi;
        float var = sh2[0] / (float)Mi - m * m;
        mu[z * 256 + j] = m;
        rstd[z * 256 + j] = rsqrtf(var + 1e-5f);
    }
}

__global__ __launch_bounds__(256) void norm_all(const float* h1F, const float* mu, const float* rstd,
                                                const float* ga, const float* gb, const float* gc,
                                                const float* ba, const float* bb, const float* bc,
                                                bf16* nh1B)
{
    int r = blockIdx.x;
    int n = threadIdx.x;
    int z = (r < N04) ? 0 : (r < N04 + N07) ? 1 : 2;
    const float* g  = (z == 0) ? ga : (z == 1) ? gb : gc;
    const float* bt = (z == 0) ? ba : (z == 1) ? bb : bc;
    float v = (h1F[(size_t)r * 256 + n] - mu[z * 256 + n]) * rstd[z * 256 + n] * g[n] + bt[n];
    nh1B[(size_t)r * 256 + n] = __float2bfloat16(v);
}

extern "C" void kernel_launch(void* const* d_in, const int* in_sizes, int n_in,
                              void* d_out, int out_size, void* d_ws, size_t ws_size,
                              hipStream_t stream)
{
    char* wp = (char*)d_ws;
    auto carve = [&](size_t bytes) -> void* {
        void* p = (void*)wp;
        wp += (bytes + 255) & ~(size_t)255;
        return p;
    };
    float* arena = (float*)carve((size_t)g_tbl.off[NT] * 4);
    int*   flag  = (int*)carve(256);
    float* h_a   = (float*)carve((size_t)BN * HID * 4);
    float* h_b   = (float*)carve((size_t)BN * HID * 4);
    bf16*  hb_a  = (bf16*)carve((size_t)BN * HID * 2);
    bf16*  hb_b  = (bf16*)carve((size_t)BN * HID * 2);
    bf16*  rh    = (bf16*)carve((size_t)BN * HID * 2);
    bf16*  uhc   = (bf16*)carve((size_t)BN * HID * 2);
    float* ubuf  = (float*)carve((size_t)BN * HID * 4);
    bf16*  WgT   = (bf16*)carve((size_t)512 * 256 * 2);
    bf16*  WcT   = (bf16*)carve((size_t)256 * 256 * 2);
    bf16*  WlT   = (bf16*)carve((size_t)256 * 256 * 2);
    bf16*  vecB  = (bf16*)carve((size_t)MTOT * 128 * 2);
    bf16*  adjB  = (bf16*)carve((size_t)(N04 * 320 + N07 * 896 + N08 * 192) * 2);
    bf16*  W1T   = (bf16*)carve((size_t)3 * 256 * 128 * 2);
    bf16*  W2T   = (bf16*)carve((size_t)3 * 256 * 256 * 2);
    bf16*  featWT= (bf16*)carve((size_t)256 * 256 * 2);
    bf16*  linW2T= (bf16*)carve((size_t)256 * 256 * 2);
    bf16*  outWT = (bf16*)carve((size_t)64 * 256 * 2);
    float* h0F   = (float*)carve((size_t)MTOT * 256 * 4);
    bf16*  h0T   = (bf16*)carve((size_t)256 * H0T_LD * 2);
    float* h1F   = (float*)carve((size_t)MTOT * 256 * 4);
    bf16*  nh1B  = (bf16*)carve((size_t)MTOT * 256 * 2);
    float* degb  = (float*)carve((size_t)MTOT * 4);
    float* mub   = (float*)carve(3 * 256 * 4);
    float* rstdb = (float*)carve(3 * 256 * 4);
    bf16*  f4B   = (bf16*)carve((size_t)N04 * 256 * 2);
    bf16*  fpreB = (bf16*)carve((size_t)N04 * 256 * 2);
    float* fp2   = (float*)carve((size_t)N04 * 256 * 4);

    // --- dtype sniff + canonical fp32 conversion ---
    sniff_kernel<<<1, 256, 0, stream>>>((const unsigned short*)d_in[0], flag);
    Ptrs ptrs;
    for (int i = 0; i < NT; ++i) ptrs.p[i] = d_in[i];
    convert_all<<<g_tbl.blk[NT], 256, 0, stream>>>(ptrs, arena, flag);

    auto A = [&](int i) -> const float* { return arena + g_tbl.off[i]; };

    // --- operand prep ---
    prep_weights<<<1024, 256, 0, stream>>>(A(28), A(30), A(34), WgT, WcT, WlT);
    prep_adjB<<<dim3(N07, 1, 3), 256, 0, stream>>>(A(4), A(5), A(6), adjB);
    prep_transposes<<<(PREP_T_TOT + 255) / 256, 256, 0, stream>>>(
        A(0), A(1), A(2), A(7), A(14), A(21), A(9), A(16), A(23),
        A(32), A(34), A(36), vecB, W1T, W2T, featWT, linW2T, outWT);

    hipMemsetAsync(h_a, 0, (size_t)BN * HID * 4, stream);
    hipMemsetAsync(hb_a, 0, (size_t)BN * HID * 2, stream);
    hipMemsetAsync(h0T, 0, (size_t)256 * H0T_LD * 2, stream);

    const size_t o_f4 = (size_t)B_ * N04 * PRE;
    const size_t o_f7 = o_f4 + (size_t)N04 * ENC;
    const size_t o_f8 = o_f7 + (size_t)N07 * ENC;

    // --- deg ---
    deg_all<<<dim3(N07, 1, 3), 64, 0, stream>>>(A(4), A(5), A(6), degb);

    // --- E1: h0 = vec@W1 + b1 ---
    {
        GemmZ p;
        for (int z = 0; z < 3; ++z) {
            p.A[z] = (const unsigned short*)(vecB + (size_t)c_Moff[z] * 128);
            p.BT[z] = (const unsigned short*)(W1T + (size_t)z * 256 * 128);
            p.M[z] = c_Mi[z]; p.K[z] = 128; p.lda[z] = 128; p.ldb[z] = 128;
        }
        EPg1 ep{{A(8), A(15), A(22)}, h0F, h0T};
        gemm_mfma64<<<dim3(14, 4, 3), 256, 0, stream>>>(p, 256, ep);
    }
    // --- E2: h1 = (adj@h0)/deg + eps*h0 ---
    {
        GemmZ p;
        for (int z = 0; z < 3; ++z) {
            p.A[z] = (const unsigned short*)(adjB + c_Aoff[z]);
            p.BT[z] = (const unsigned short*)(h0T + c_Cb[z]);
            p.M[z] = c_Mi[z]; p.K[z] = c_Kp[z]; p.lda[z] = c_Kp[z]; p.ldb[z] = H0T_LD;
        }
        EPg2 ep{degb, h0F, h1F, {A(13), A(20), A(27)}};
        gemm_mfma64<<<dim3(14, 4, 3), 256, 0, stream>>>(p, 256, ep);
    }
    // --- BN stats + normalize ---
    stats_all<<<dim3(256, 1, 3), 256, 0, stream>>>(h1F, mub, rstdb);
    norm_all<<<MTOT, 256, 0, stream>>>(h1F, mub, rstdb, A(11), A(18), A(25), A(12), A(19), A(26), nh1B);
    // --- E3: f = nh1@W2 + b2 ---
    {
        GemmZ p;
        for (int z = 0; z < 3; ++z) {
            p.A[z] = (const unsigned short*)(nh1B + (size_t)c_Moff[z] * 256);
            p.BT[z] = (const unsigned short*)(W2T + (size_t)z * 256 * 256);
            p.M[z] = c_Mi[z]; p.K[z] = 256; p.lda[z] = 256; p.ldb[z] = 256;
        }
        EPg3 ep{{A(10), A(17), A(24)}, d_out, {o_f4, o_f7, o_f8}, flag, f4B};
        gemm_mfma64<<<dim3(14, 4, 3), 256, 0, stream>>>(p, 256, ep);
    }
    // --- fp2 = (f4@featW + featb) @ linW[256:512] ---
    {
        GemmZ p{};
        p.A[0] = (const unsigned short*)f4B; p.BT[0] = (const unsigned short*)featWT;
        p.M[0] = N04; p.K[0] = 256; p.lda[0] = 256; p.ldb[0] = 256;
        gemm_mfma64<<<dim3(5, 4, 1), 256, 0, stream>>>(p, 256, EPfp2a{A(33), fpreB});
        p.A[0] = (const unsigned short*)fpreB; p.BT[0] = (const unsigned short*)linW2T;
        gemm_mfma64<<<dim3(5, 4, 1), 256, 0, stream>>>(p, 256, EPfp2b{fp2});
    }

    // --- GRU scan (128-tile MFMA) ---
    const float* feat = A(3);
    float* hcF = h_a;  bf16* hcB = hb_a;
    float* hnF = h_b;  bf16* hnB = hb_b;
    const int MB = (BN + 127) / 128;
    for (int s = 0; s < S_; ++s) {
        gemm_mfma<<<dim3(MB, 4), 256, 0, stream>>>(BN, (const unsigned short*)hcB, (const unsigned short*)WgT,
            EPgates2{rh, ubuf, hcF, A(29), A(28), feat, s});
        gemm_mfma<<<dim3(MB, 2), 256, 0, stream>>>(BN, (const unsigned short*)rh, (const unsigned short*)WcT,
            EPcand2{uhc, ubuf, hcF, A(31), A(30), feat, s});
        gemm_mfma<<<dim3(MB, 2), 256, 0, stream>>>(BN, (const unsigned short*)uhc, (const unsigned short*)WlT,
            EPlin2{hnF, hnB, A(35), fp2});
        float* tf = hcF; hcF = hnF; hnF = tf;
        bf16*  tb = hcB; hcB = hnB; hnB = tb;
    }

    // --- pred = h@outW + outb (MFMA, N padded, guard n<12) ---
    {
        GemmZ p{};
        p.A[0] = (const unsigned short*)hcB; p.BT[0] = (const unsigned short*)outWT;
        p.M[0] = BN; p.K[0] = 256; p.lda[0] = 256; p.ldb[0] = 256;
        gemm_mfma64<<<dim3((BN + 63) / 64, 1, 1), 256, 0, stream>>>(p, PRE, EPpred{A(37), d_out, flag});
    }
}

// Round 6
// 938.982 us; speedup vs baseline: 5.6732x; 1.7290x over previous
//
#include <hip/hip_runtime.h>
#include <hip/hip_bf16.h>
#include <math.h>

using bf16 = __hip_bfloat16;
using short8  = __attribute__((ext_vector_type(8))) short;
using float4v = __attribute__((ext_vector_type(4))) float;

#define B_   64
#define S_   12
#define N04  307
#define N07  883
#define N08  170
#define BN   (B_ * N04)        // 19648
#define HID  256
#define ENC  256
#define PRE  12
#define UOFF (N04 * HID)       // 78592 flat split point

// extractor geometry (K padded to x64 for MFMA)
// plain constexpr (NOT __constant__): host reads these; __constant__ host shadow is zero-init.
constexpr int c_Mi[3]   = {N04, N07, N08};
constexpr int c_Kp[3]   = {320, 896, 192};
constexpr int c_Moff[3] = {0, N04, N04 + N07};
constexpr int c_Aoff[3] = {0, N04 * 320, N04 * 320 + N07 * 896};
constexpr int c_Cb[3]   = {0, 320, 320 + 896};
#define MTOT  (N04 + N07 + N08)   // 1360
#define H0T_LD 1408

// ---------------- static tensor tables ----------------
#define NT 38
constexpr int g_sz[NT] = {
    39296, 113024, 21760, 235776, 94249, 779689, 28900,
    32768, 256, 65536, 256, 256, 256, 1,
    32768, 256, 65536, 256, 256, 256, 1,
    32768, 256, 65536, 256, 256, 256, 1,
    131584, 512, 65792, 256, 65536, 1, 131072, 256, 3072, 12
};
struct Tables { int off[NT + 1]; int blk[NT + 1]; };
constexpr Tables mk_tables() {
    Tables t{};
    t.off[0] = 0; t.blk[0] = 0;
    for (int i = 0; i < NT; ++i) {
        t.off[i + 1] = t.off[i] + g_sz[i];
        t.blk[i + 1] = t.blk[i] + (g_sz[i] + 1023) / 1024;
    }
    return t;
}
constexpr Tables g_tbl = mk_tables();

// fast sigmoid/tanh (saturation-safe: exp->inf => rcp->0)
static __device__ __forceinline__ float fsigmoid(float t) {
    return __builtin_amdgcn_rcpf(1.f + __expf(-t));
}
static __device__ __forceinline__ float ftanh(float t) {
    return 1.f - 2.f * __builtin_amdgcn_rcpf(__expf(2.f * t) + 1.f);
}

// ---------------- dtype sniffer ----------------
__global__ void sniff_kernel(const unsigned short* raw, int* flag)
{
    __shared__ int sh[256];
    int t = threadIdx.x, cnt = 0;
    for (int i = t; i < 2048; i += 256) {
        unsigned int w = ((unsigned int)raw[i]) << 16;
        float a = fabsf(__uint_as_float(w));
        if (a > 1e-3f && a < 100.f) cnt++;
    }
    sh[t] = cnt; __syncthreads();
    for (int off = 128; off > 0; off >>= 1) {
        if (t < off) sh[t] += sh[t + off];
        __syncthreads();
    }
    if (t == 0) *flag = (sh[0] > 1536) ? 1 : 0;
}

struct Ptrs { const void* p[NT]; };

__global__ __launch_bounds__(256) void convert_all(Ptrs a, float* arena, const int* flag)
{
    const int bf = *flag;
    int b = blockIdx.x;
    int t = 0;
    while (b >= g_tbl.blk[t + 1]) ++t;
    const int base = (b - g_tbl.blk[t]) * 1024;
    const int n = g_sz[t];
    const void* src = a.p[t];
    float* dst = arena + g_tbl.off[t];
#pragma unroll
    for (int k = 0; k < 4; ++k) {
        int j = base + k * 256 + threadIdx.x;
        if (j < n)
            dst[j] = bf ? __bfloat162float(((const bf16*)src)[j]) : ((const float*)src)[j];
    }
}

// ---------------- weight prep: GRU transposed bf16 B matrices ----------------
__global__ __launch_bounds__(256) void prep_weights(const float* w1, const float* w2, const float* wl,
                                                    bf16* WgT, bf16* WcT, bf16* WlT)
{
    int id = blockIdx.x * 256 + threadIdx.x;
    if (id < 131072) {
        int n = id >> 8, k = id & 255;
        WgT[id] = __float2bfloat16(w1[(size_t)(1 + k) * 512 + n]);
    } else if (id < 196608) {
        int r = id - 131072; int n = r >> 8, k = r & 255;
        WcT[r] = __float2bfloat16(w2[(size_t)(1 + k) * 256 + n]);
    } else if (id < 262144) {
        int r = id - 196608; int n = r >> 8, k = r & 255;
        WlT[r] = __float2bfloat16(wl[(size_t)k * 256 + n]);
    }
}

// ---------------- extractor operand prep ----------------
__global__ __launch_bounds__(256) void prep_adjB(const float* a4, const float* a7, const float* a8, bf16* adjB)
{
    int z = blockIdx.z;
    int Mi = c_Mi[z], Kp = c_Kp[z];
    int m = blockIdx.x;
    if (m >= Mi) return;
    const float* src = (z == 0) ? a4 : (z == 1) ? a7 : a8;
    bf16* dst = adjB + c_Aoff[z] + (size_t)m * Kp;
    for (int c = threadIdx.x; c < Kp; c += 256)
        dst[c] = (c < Mi) ? __float2bfloat16(src[(size_t)m * Mi + c]) : __float2bfloat16(0.f);
}

__global__ __launch_bounds__(256) void prep_transposes(
    const float* v4, const float* v7, const float* v8,
    const float* w1a, const float* w1b, const float* w1c,
    const float* w2a, const float* w2b, const float* w2c,
    const float* featW, const float* linW, const float* outW,
    bf16* vecB, bf16* W1T, bf16* W2T, bf16* featWT, bf16* linW2T, bf16* outWT)
{
    int id = blockIdx.x * 256 + threadIdx.x;
    if (id < 174080) {                       // vecB [1360][128]
        int r = id >> 7, c = id & 127;
        float v = (r < N04) ? v4[(size_t)r * 128 + c]
                : (r < N04 + N07) ? v7[(size_t)(r - N04) * 128 + c]
                : v8[(size_t)(r - N04 - N07) * 128 + c];
        vecB[id] = __float2bfloat16(v);
    } else if (id < 174080 + 98304) {        // W1T [3][256][128]
        int r = id - 174080; int z = r >> 15; int rem = r & 32767;
        int n = rem >> 7, k = rem & 127;
        const float* w = (z == 0) ? w1a : (z == 1) ? w1b : w1c;
        W1T[r] = __float2bfloat16(w[(size_t)k * 256 + n]);
    } else if (id < 272384 + 196608) {       // W2T [3][256][256]
        int r = id - 272384; int z = r >> 16; int rem = r & 65535;
        int n = rem >> 8, k = rem & 255;
        const float* w = (z == 0) ? w2a : (z == 1) ? w2b : w2c;
        W2T[r] = __float2bfloat16(w[(size_t)k * 256 + n]);
    } else if (id < 468992 + 65536) {        // featWT
        int r = id - 468992; int n = r >> 8, k = r & 255;
        featWT[r] = __float2bfloat16(featW[(size_t)k * 256 + n]);
    } else if (id < 534528 + 65536) {        // linW2T = linW[256:512]^T
        int r = id - 534528; int n = r >> 8, k = r & 255;
        linW2T[r] = __float2bfloat16(linW[(size_t)(256 + k) * 256 + n]);
    } else if (id < 600064 + 16384) {        // outWT [64][256], rows 12..63 zero
        int r = id - 600064; int p = r >> 8, k = r & 255;
        outWT[r] = __float2bfloat16((p < PRE) ? outW[(size_t)k * PRE + p] : 0.f);
    }
}
#define PREP_T_TOT (600064 + 16384)

// ---------------- 64x64-tile MFMA GEMM, z-merged, runtime K ----------------
struct GemmZ {
    const unsigned short* A[3];
    const unsigned short* BT[3];
    int M[3]; int K[3]; int lda[3]; int ldb[3];
};

template <typename EP>
__global__ __launch_bounds__(256) void gemm_mfma64(GemmZ p, int Nv, EP ep)
{
    const int z = blockIdx.z;
    const int M = p.M[z], K = p.K[z], lda = p.lda[z], ldb = p.ldb[z];
    const int m0 = blockIdx.x * 64;
    const int n0 = blockIdx.y * 64;
    if (m0 >= M) return;
    __shared__ __align__(16) unsigned short As[64 * 72];
    __shared__ __align__(16) unsigned short Bs[64 * 72];
    const int t = threadIdx.x;
    const int srow  = t >> 2;           // 0..63
    const int skoff = (t & 3) * 16;     // 0,16,32,48 shorts
    const int lane = t & 63;
    const int w  = t >> 6;
    const int wm = (w & 1) * 32;
    const int wn = (w >> 1) * 32;
    const int l15 = lane & 15;
    const int l4  = lane >> 4;

    float4v acc[2][2];
#pragma unroll
    for (int i = 0; i < 2; ++i)
#pragma unroll
        for (int j = 0; j < 2; ++j) acc[i][j] = (float4v)(0.f);

    const int gm = m0 + srow;
    const bool avalid = (gm < M);
    const unsigned short* aptr = p.A[z]  + (size_t)gm * lda + skoff;
    const unsigned short* bptr = p.BT[z] + (size_t)(n0 + srow) * ldb + skoff;
    unsigned short* asw = &As[srow * 72 + skoff];
    unsigned short* bsw = &Bs[srow * 72 + skoff];
    const uint4 z4 = {0, 0, 0, 0};

    for (int kt = 0; kt < K; kt += 64) {
        uint4 av0 = avalid ? *(const uint4*)(aptr + kt)     : z4;
        uint4 av1 = avalid ? *(const uint4*)(aptr + kt + 8) : z4;
        uint4 bv0 = *(const uint4*)(bptr + kt);
        uint4 bv1 = *(const uint4*)(bptr + kt + 8);
        __syncthreads();
        *(uint4*)(asw)     = av0;
        *(uint4*)(asw + 8) = av1;
        *(uint4*)(bsw)     = bv0;
        *(uint4*)(bsw + 8) = bv1;
        __syncthreads();
#pragma unroll
        for (int ks = 0; ks < 2; ++ks) {
            short8 af[2], bq[2];
#pragma unroll
            for (int mi = 0; mi < 2; ++mi)
                af[mi] = *(const short8*)&As[(wm + mi * 16 + l15) * 72 + ks * 32 + l4 * 8];
#pragma unroll
            for (int ni = 0; ni < 2; ++ni)
                bq[ni] = *(const short8*)&Bs[(wn + ni * 16 + l15) * 72 + ks * 32 + l4 * 8];
#pragma unroll
            for (int mi = 0; mi < 2; ++mi)
#pragma unroll
                for (int ni = 0; ni < 2; ++ni)
                    acc[mi][ni] = __builtin_amdgcn_mfma_f32_16x16x32_bf16(af[mi], bq[ni], acc[mi][ni], 0, 0, 0);
        }
    }
#pragma unroll
    for (int mi = 0; mi < 2; ++mi) {
#pragma unroll
        for (int r = 0; r < 4; ++r) {
            int m = m0 + wm + mi * 16 + l4 * 4 + r;
            if (m >= M) continue;
#pragma unroll
            for (int ni = 0; ni < 2; ++ni) {
                int n = n0 + wn + ni * 16 + l15;
                if (n < Nv) ep(z, m, n, acc[mi][ni][r]);
            }
        }
    }
}

// ---------------- extractor epilogues ----------------
struct EPg1 {   // h0 = vec@W1 + b1 ; write fp32 + transposed bf16
    const float* b1[3]; float* h0F; bf16* h0T;
    __device__ void operator()(int z, int m, int n, float v) const {
        v += b1[z][n];
        int gr = c_Moff[z] + m;
        h0F[(size_t)gr * 256 + n] = v;
        h0T[(size_t)n * H0T_LD + c_Cb[z] + m] = __float2bfloat16(v);
    }
};
struct EPg2 {   // h1 = pooled/deg + eps*h0
    const float* deg; const float* h0F; float* h1F; const float* eps[3];
    __device__ void operator()(int z, int m, int n, float v) const {
        int gr = c_Moff[z] + m;
        h1F[(size_t)gr * 256 + n] = v / deg[gr] + eps[z][0] * h0F[(size_t)gr * 256 + n];
    }
};
struct EPg3 {   // f = norm(h1)@W2 + b2 -> d_out (+ f4 bf16 copy for fp2)
    const float* b2[3]; void* outbase; size_t ooff[3]; const int* flag; bf16* f4B;
    __device__ void operator()(int z, int m, int n, float v) const {
        v += b2[z][n];
        size_t i = ooff[z] + (size_t)m * 256 + n;
        if (*flag) ((bf16*)outbase)[i] = __float2bfloat16(v);
        else       ((float*)outbase)[i] = v;
        if (z == 0) f4B[(size_t)m * 256 + n] = __float2bfloat16(v);
    }
};
struct EPfp2a { // fpre = f4@featW + featb (bf16)
    const float* sb; bf16* fpreB;
    __device__ void operator()(int z, int m, int n, float v) const {
        fpreB[(size_t)m * 256 + n] = __float2bfloat16(v + sb[0]);
    }
};
struct EPfp2b { // fp2 = fpre@linW[256:] (fp32)
    float* fp2;
    __device__ void operator()(int z, int m, int n, float v) const {
        fp2[(size_t)m * 256 + n] = v;
    }
};
struct EPpred { // pred = h@outW + outb -> d_out
    const float* ob; void* outbase; const int* flag;
    __device__ void operator()(int z, int m, int n, float v) const {
        v += ob[n];
        size_t i = (size_t)m * PRE + n;
        if (*flag) ((bf16*)outbase)[i] = __float2bfloat16(v);
        else       ((float*)outbase)[i] = v;
    }
};

// ---------------- GRU epilogues (all-bf16 state) ----------------
struct EPgates3 {   // g = sigmoid(.); r-half -> rh = r*h (bf16), u-half -> ub (bf16)
    bf16* rh; bf16* ub; const bf16* hB;
    const float* b1; const float* w1r0; const float* feat; int s;
    __device__ void operator()(int z, int m, int n, float v) const {
        int b = m / N04, nn = m - b * N04;
        float x = feat[((size_t)b * S_ + s) * N04 + nn];
        float g = fsigmoid(v + b1[n] + x * w1r0[n]);
        int p = nn * 512 + n;                 // flat per-batch gate index
        int base = b * UOFF;
        if (p < UOFF) {
            int idx = base + p;
            rh[idx] = __float2bfloat16(g * __bfloat162float(hB[idx]));
        } else {
            ub[base + (p - UOFF)] = __float2bfloat16(g);
        }
    }
};
struct EPcand3 {    // c = tanh(.); uhc = u*h + (1-u)*c (bf16)
    bf16* uhc; const bf16* ub; const bf16* hB;
    const float* b2; const float* w2r0; const float* feat; int s;
    __device__ void operator()(int z, int m, int n, float v) const {
        int b = m / N04, nn = m - b * N04;
        float x = feat[((size_t)b * S_ + s) * N04 + nn];
        float c = ftanh(v + b2[n] + x * w2r0[n]);
        size_t idx = (size_t)m * 256 + n;
        float u = __bfloat162float(ub[idx]);
        float h = __bfloat162float(hB[idx]);
        uhc[idx] = __float2bfloat16(u * h + (1.f - u) * c);
    }
};
struct EPlin3 {     // h_next = v + lin_b + fp2 (bf16)
    bf16* hB; const float* lb; const float* fp2;
    __device__ void operator()(int z, int m, int n, float v) const {
        int nn = m % N04;
        hB[(size_t)m * 256 + n] = __float2bfloat16(v + lb[n] + fp2[(size_t)nn * 256 + n]);
    }
};

// ---------------- merged small kernels ----------------
__global__ void deg_all(const float* a4, const float* a7, const float* a8, float* deg)
{
    int z = blockIdx.z;
    int Mi = c_Mi[z];
    int row = blockIdx.x;
    if (row >= Mi) return;
    const float* adj = (z == 0) ? a4 : (z == 1) ? a7 : a8;
    float s = 0.f;
    for (int j = threadIdx.x; j < Mi; j += 64) s += adj[(size_t)row * Mi + j];
#pragma unroll
    for (int off = 32; off > 0; off >>= 1) s += __shfl_down(s, off, 64);
    if (threadIdx.x == 0) deg[c_Moff[z] + row] = s;
}

__global__ __launch_bounds__(256) void stats_all(const float* h1F, float* mu, float* rstd)
{
    int z = blockIdx.z;
    int Mi = c_Mi[z], moff = c_Moff[z];
    int j = blockIdx.x;
    int t = threadIdx.x;
    float s = 0.f, ss = 0.f;
    for (int i = t; i < Mi; i += 256) {
        float v = h1F[(size_t)(moff + i) * 256 + j];
        s += v; ss += v * v;
    }
    __shared__ float sh[256], sh2[256];
    sh[t] = s; sh2[t] = ss;
    __syncthreads();
    for (int off = 128; off > 0; off >>= 1) {
        if (t < off) { sh[t] += sh[t + off]; sh2[t] += sh2[t + off]; }
        __syncthreads();
    }
    if (t == 0) {
        float m = sh[0] / (float)Mi;
        float var = sh2[0] / (float)Mi - m * m;
        mu[z * 256 + j] = m;
        rstd[z * 256 + j] = rsqrtf(var + 1e-5f);
    }
}

__global__ __launch_bounds__(256) void norm_all(const float* h1F, const float* mu, const float* rstd,
                                                const float* ga, const float* gb, const float* gc,
                                                const float* ba, const float* bb, const float* bc,
                                                bf16* nh1B)
{
    int r = blockIdx.x;
    int n = threadIdx.x;
    int z = (r < N04) ? 0 : (r < N04 + N07) ? 1 : 2;
    const float* g  = (z == 0) ? ga : (z == 1) ? gb : gc;
    const float* bt = (z == 0) ? ba : (z == 1) ? bb : bc;
    float v = (h1F[(size_t)r * 256 + n] - mu[z * 256 + n]) * rstd[z * 256 + n] * g[n] + bt[n];
    nh1B[(size_t)r * 256 + n] = __float2bfloat16(v);
}

extern "C" void kernel_launch(void* const* d_in, const int* in_sizes, int n_in,
                              void* d_out, int out_size, void* d_ws, size_t ws_size,
                              hipStream_t stream)
{
    char* wp = (char*)d_ws;
    auto carve = [&](size_t bytes) -> void* {
        void* p = (void*)wp;
        wp += (bytes + 255) & ~(size_t)255;
        return p;
    };
    float* arena = (float*)carve((size_t)g_tbl.off[NT] * 4);
    int*   flag  = (int*)carve(256);
    bf16*  hb_a  = (bf16*)carve((size_t)BN * HID * 2);
    bf16*  hb_b  = (bf16*)carve((size_t)BN * HID * 2);
    bf16*  rh    = (bf16*)carve((size_t)BN * HID * 2);
    bf16*  uhc   = (bf16*)carve((size_t)BN * HID * 2);
    bf16*  ubufB = (bf16*)carve((size_t)BN * HID * 2);
    bf16*  WgT   = (bf16*)carve((size_t)512 * 256 * 2);
    bf16*  WcT   = (bf16*)carve((size_t)256 * 256 * 2);
    bf16*  WlT   = (bf16*)carve((size_t)256 * 256 * 2);
    bf16*  vecB  = (bf16*)carve((size_t)MTOT * 128 * 2);
    bf16*  adjB  = (bf16*)carve((size_t)(N04 * 320 + N07 * 896 + N08 * 192) * 2);
    bf16*  W1T   = (bf16*)carve((size_t)3 * 256 * 128 * 2);
    bf16*  W2T   = (bf16*)carve((size_t)3 * 256 * 256 * 2);
    bf16*  featWT= (bf16*)carve((size_t)256 * 256 * 2);
    bf16*  linW2T= (bf16*)carve((size_t)256 * 256 * 2);
    bf16*  outWT = (bf16*)carve((size_t)64 * 256 * 2);
    float* h0F   = (float*)carve((size_t)MTOT * 256 * 4);
    bf16*  h0T   = (bf16*)carve((size_t)256 * H0T_LD * 2);
    float* h1F   = (float*)carve((size_t)MTOT * 256 * 4);
    bf16*  nh1B  = (bf16*)carve((size_t)MTOT * 256 * 2);
    float* degb  = (float*)carve((size_t)MTOT * 4);
    float* mub   = (float*)carve(3 * 256 * 4);
    float* rstdb = (float*)carve(3 * 256 * 4);
    bf16*  f4B   = (bf16*)carve((size_t)N04 * 256 * 2);
    bf16*  fpreB = (bf16*)carve((size_t)N04 * 256 * 2);
    float* fp2   = (float*)carve((size_t)N04 * 256 * 4);

    // --- dtype sniff + canonical fp32 conversion ---
    sniff_kernel<<<1, 256, 0, stream>>>((const unsigned short*)d_in[0], flag);
    Ptrs ptrs;
    for (int i = 0; i < NT; ++i) ptrs.p[i] = d_in[i];
    convert_all<<<g_tbl.blk[NT], 256, 0, stream>>>(ptrs, arena, flag);

    auto A = [&](int i) -> const float* { return arena + g_tbl.off[i]; };

    // --- operand prep ---
    prep_weights<<<1024, 256, 0, stream>>>(A(28), A(30), A(34), WgT, WcT, WlT);
    prep_adjB<<<dim3(N07, 1, 3), 256, 0, stream>>>(A(4), A(5), A(6), adjB);
    prep_transposes<<<(PREP_T_TOT + 255) / 256, 256, 0, stream>>>(
        A(0), A(1), A(2), A(7), A(14), A(21), A(9), A(16), A(23),
        A(32), A(34), A(36), vecB, W1T, W2T, featWT, linW2T, outWT);

    hipMemsetAsync(hb_a, 0, (size_t)BN * HID * 2, stream);
    hipMemsetAsync(h0T, 0, (size_t)256 * H0T_LD * 2, stream);

    const size_t o_f4 = (size_t)B_ * N04 * PRE;
    const size_t o_f7 = o_f4 + (size_t)N04 * ENC;
    const size_t o_f8 = o_f7 + (size_t)N07 * ENC;

    // --- deg ---
    deg_all<<<dim3(N07, 1, 3), 64, 0, stream>>>(A(4), A(5), A(6), degb);

    // --- E1: h0 = vec@W1 + b1 ---
    {
        GemmZ p;
        for (int z = 0; z < 3; ++z) {
            p.A[z] = (const unsigned short*)(vecB + (size_t)c_Moff[z] * 128);
            p.BT[z] = (const unsigned short*)(W1T + (size_t)z * 256 * 128);
            p.M[z] = c_Mi[z]; p.K[z] = 128; p.lda[z] = 128; p.ldb[z] = 128;
        }
        EPg1 ep{{A(8), A(15), A(22)}, h0F, h0T};
        gemm_mfma64<<<dim3(14, 4, 3), 256, 0, stream>>>(p, 256, ep);
    }
    // --- E2: h1 = (adj@h0)/deg + eps*h0 ---
    {
        GemmZ p;
        for (int z = 0; z < 3; ++z) {
            p.A[z] = (const unsigned short*)(adjB + c_Aoff[z]);
            p.BT[z] = (const unsigned short*)(h0T + c_Cb[z]);
            p.M[z] = c_Mi[z]; p.K[z] = c_Kp[z]; p.lda[z] = c_Kp[z]; p.ldb[z] = H0T_LD;
        }
        EPg2 ep{degb, h0F, h1F, {A(13), A(20), A(27)}};
        gemm_mfma64<<<dim3(14, 4, 3), 256, 0, stream>>>(p, 256, ep);
    }
    // --- BN stats + normalize ---
    stats_all<<<dim3(256, 1, 3), 256, 0, stream>>>(h1F, mub, rstdb);
    norm_all<<<MTOT, 256, 0, stream>>>(h1F, mub, rstdb, A(11), A(18), A(25), A(12), A(19), A(26), nh1B);
    // --- E3: f = nh1@W2 + b2 ---
    {
        GemmZ p;
        for (int z = 0; z < 3; ++z) {
            p.A[z] = (const unsigned short*)(nh1B + (size_t)c_Moff[z] * 256);
            p.BT[z] = (const unsigned short*)(W2T + (size_t)z * 256 * 256);
            p.M[z] = c_Mi[z]; p.K[z] = 256; p.lda[z] = 256; p.ldb[z] = 256;
        }
        EPg3 ep{{A(10), A(17), A(24)}, d_out, {o_f4, o_f7, o_f8}, flag, f4B};
        gemm_mfma64<<<dim3(14, 4, 3), 256, 0, stream>>>(p, 256, ep);
    }
    // --- fp2 = (f4@featW + featb) @ linW[256:512] ---
    {
        GemmZ p{};
        p.A[0] = (const unsigned short*)f4B; p.BT[0] = (const unsigned short*)featWT;
        p.M[0] = N04; p.K[0] = 256; p.lda[0] = 256; p.ldb[0] = 256;
        gemm_mfma64<<<dim3(5, 4, 1), 256, 0, stream>>>(p, 256, EPfp2a{A(33), fpreB});
        p.A[0] = (const unsigned short*)fpreB; p.BT[0] = (const unsigned short*)linW2T;
        gemm_mfma64<<<dim3(5, 4, 1), 256, 0, stream>>>(p, 256, EPfp2b{fp2});
    }

    // --- GRU scan: 64x64-tile MFMA, all-bf16 state ---
    const float* feat = A(3);
    bf16* hcB = hb_a;
    bf16* hnB = hb_b;
    for (int s = 0; s < S_; ++s) {
        GemmZ p{};
        p.M[0] = BN; p.K[0] = 256; p.lda[0] = 256; p.ldb[0] = 256;
        p.A[0] = (const unsigned short*)hcB; p.BT[0] = (const unsigned short*)WgT;
        gemm_mfma64<<<dim3(BN / 64, 8, 1), 256, 0, stream>>>(p, 512,
            EPgates3{rh, ubufB, hcB, A(29), A(28), feat, s});
        p.A[0] = (const unsigned short*)rh; p.BT[0] = (const unsigned short*)WcT;
        gemm_mfma64<<<dim3(BN / 64, 4, 1), 256, 0, stream>>>(p, 256,
            EPcand3{uhc, ubufB, hcB, A(31), A(30), feat, s});
        p.A[0] = (const unsigned short*)uhc; p.BT[0] = (const unsigned short*)WlT;
        gemm_mfma64<<<dim3(BN / 64, 4, 1), 256, 0, stream>>>(p, 256,
            EPlin3{hnB, A(35), fp2});
        bf16* tb = hcB; hcB = hnB; hnB = tb;
    }

    // --- pred = h@outW + outb (MFMA, N padded, guard n<12) ---
    {
        GemmZ p{};
        p.A[0] = (const unsigned short*)hcB; p.BT[0] = (const unsigned short*)outWT;
        p.M[0] = BN; p.K[0] = 256; p.lda[0] = 256; p.ldb[0] = 256;
        gemm_mfma64<<<dim3(BN / 64, 1, 1), 256, 0, stream>>>(p, PRE, EPpred{A(37), d_out, flag});
    }
}